// Round 10
// baseline (345.352 us; speedup 1.0000x reference)
//
#include <hip/hip_runtime.h>
#include <cstdint>
#include <cstddef>

// ---------- types / helpers ----------
typedef __bf16 bf16x8 __attribute__((ext_vector_type(8)));
typedef float  f32x4  __attribute__((ext_vector_type(4)));
typedef unsigned short us;

#define DEV static __device__ __forceinline__

DEV us f2bf(float f) {
    unsigned int u = __builtin_bit_cast(unsigned int, f);
    u += 0x7FFFu + ((u >> 16) & 1u);   // RNE
    return (us)(u >> 16);
}
DEV unsigned int pack2bf(float a, float b) {   // [lo=a, hi=b], round-half-up (cheap)
    unsigned int ua = __builtin_bit_cast(unsigned int, a) + 0x8000u;
    unsigned int ub = __builtin_bit_cast(unsigned int, b) + 0x8000u;
    return (ua >> 16) | (ub & 0xFFFF0000u);    // -> v_perm_b32
}

DEV void gll16(const void* g, void* l) {   // 16B global->LDS direct (wave: +lane*16)
    __builtin_amdgcn_global_load_lds(
        (const __attribute__((address_space(1))) unsigned int*)g,
        (__attribute__((address_space(3))) unsigned int*)l, 16, 0, 0);
}

DEV bf16x8 ld_frag(const us* p) {
    return __builtin_bit_cast(bf16x8, *reinterpret_cast<const uint4*>(p));
}

// ---------- problem constants ----------
#define BB 4
#define TT 2048
#define CC 768
#define NH 12
#define DH 64
#define MM (BB*TT)          // 8192
#define QSCALE 0.1803368801111144f   // 0.125 * log2(e): softmax via exp2

// ---------- cast f32 -> bf16 ----------
__global__ __launch_bounds__(256)
void cast_k(const float* __restrict__ x, us* __restrict__ xb, int n4)
{
    int i = blockIdx.x * 256 + threadIdx.x;
    int stride = gridDim.x * 256;
    for (; i < n4; i += stride) {
        float4 f = reinterpret_cast<const float4*>(x)[i];
        ushort4 o;
        o.x = f2bf(f.x); o.y = f2bf(f.y); o.z = f2bf(f.z); o.w = f2bf(f.w);
        reinterpret_cast<ushort4*>(xb)[i] = o;
    }
}

// ---------- transpose f32 -> bf16: dst[Cc][R] = bf16(src[R][Cc]) ----------
__global__ __launch_bounds__(256)
void transpose_k(const float* __restrict__ src,
                 us* __restrict__ dst, int R, int Cc)
{
    __shared__ float tile[32][33];
    int c0 = blockIdx.x * 32, r0 = blockIdx.y * 32;
    int tx = threadIdx.x, ty = threadIdx.y;
#pragma unroll
    for (int i = 0; i < 4; ++i)
        tile[ty + i*8][tx] = src[(size_t)(r0 + ty + i*8) * Cc + c0 + tx];
    __syncthreads();
#pragma unroll
    for (int i = 0; i < 4; ++i)
        dst[(size_t)(c0 + ty + i*8) * R + r0 + tx] = f2bf(tile[tx][ty + i*8]);
}

// ---------- GEMM: C[M,N] = A[M,K](bf16) * Bt[N,K]^T + bias[N] ----------
// MODE 0: store f32 to Cout
// MODE 1: scatter qkv -> Qo(scaled)[B,H,T,D] / Ko[B,H,T,D] / Vo^T[B,H,D,T] bf16
#define BM 128
#define BN 128
#define BK 32

template<int MODE>
__global__ __launch_bounds__(256)
void gemm_bt(const us* __restrict__ A,
             const us* __restrict__ Bt,
             const float* __restrict__ bias,
             float* __restrict__ Cout,
             us* __restrict__ Qo, us* __restrict__ Ko, us* __restrict__ Vo,
             int M, int N, int K)
{
    __shared__ __align__(16) us As[BM * BK];
    __shared__ __align__(16) us Bs[BN * BK];

    const int tid  = threadIdx.x;
    const int wave = tid >> 6, lane = tid & 63;
    const int quad = lane >> 4, l16 = lane & 15;
    const int waveM = (wave >> 1) * 64, waveN = (wave & 1) * 64;
    const int m0 = blockIdx.y * BM, n0 = blockIdx.x * BN;

    const f32x4 zero4 = {0.f, 0.f, 0.f, 0.f};
    f32x4 acc[4][4];
#pragma unroll
    for (int i = 0; i < 4; ++i)
#pragma unroll
        for (int j = 0; j < 4; ++j) acc[i][j] = zero4;

    const int lrow = lane >> 2, lch = (lane & 3) * 8;
    const int nk = K / BK;
    for (int kt = 0; kt < nk; ++kt) {
#pragma unroll
        for (int c = 0; c < 2; ++c) {
            int rb = (wave * 2 + c) * 16;
            int row = rb + lrow;
            gll16(A  + (size_t)(m0 + row) * K + kt * BK + lch, &As[rb * BK]);
            gll16(Bt + (size_t)(n0 + row) * K + kt * BK + lch, &Bs[rb * BK]);
        }
        __syncthreads();

        bf16x8 af[4], bfv[4];
#pragma unroll
        for (int mi = 0; mi < 4; ++mi)
            af[mi] = *reinterpret_cast<const bf16x8*>(&As[(waveM + mi * 16 + l16) * BK + quad * 8]);
#pragma unroll
        for (int ni = 0; ni < 4; ++ni)
            bfv[ni] = *reinterpret_cast<const bf16x8*>(&Bs[(waveN + ni * 16 + l16) * BK + quad * 8]);
#pragma unroll
        for (int mi = 0; mi < 4; ++mi)
#pragma unroll
            for (int ni = 0; ni < 4; ++ni)
                acc[mi][ni] = __builtin_amdgcn_mfma_f32_16x16x32_bf16(af[mi], bfv[ni], acc[mi][ni], 0, 0, 0);
        __syncthreads();
    }

    // epilogue: C/D layout col = l16, row = quad*4 + reg
#pragma unroll
    for (int mi = 0; mi < 4; ++mi) {
#pragma unroll
        for (int ni = 0; ni < 4; ++ni) {
            int n = n0 + waveN + ni * 16 + l16;
            float bv = bias[n];
            int mg = m0 + waveM + mi * 16 + quad * 4;   // first of 4 consecutive m
            if (MODE == 0) {
#pragma unroll
                for (int reg = 0; reg < 4; ++reg)
                    Cout[(size_t)(mg + reg) * N + n] = acc[mi][ni][reg] + bv;
            } else {
                int which = n / CC, c2 = n % CC;
                int h = c2 >> 6, d = c2 & 63;
                int b = mg >> 11, t0 = mg & 2047;
                if (which == 2) {
                    // V^T [B,H,D,T]: 4 consecutive t -> one 8B store
                    ushort4 pk;
                    pk.x = f2bf(acc[mi][ni][0] + bv);
                    pk.y = f2bf(acc[mi][ni][1] + bv);
                    pk.z = f2bf(acc[mi][ni][2] + bv);
                    pk.w = f2bf(acc[mi][ni][3] + bv);
                    *reinterpret_cast<ushort4*>(Vo + ((size_t)(b * NH + h) * DH + d) * TT + t0) = pk;
                } else {
#pragma unroll
                    for (int reg = 0; reg < 4; ++reg) {
                        size_t off = ((size_t)(b * NH + h) * TT + t0 + reg) * DH + d;
                        float v = acc[mi][ni][reg] + bv;
                        if (which == 0) Qo[off] = f2bf(v * QSCALE);
                        else            Ko[off] = f2bf(v);
                    }
                }
            }
        }
    }
}

// ---------- flash attention (causal): barrier-free, wave = 16 q-rows, L2-direct K/V ----------
// Grid 768 x 256 threads (4 waves/block) = 3072 independent waves (3 waves/SIMD).
// XCD decode keeps each head's K/V on one XCD's L2. Wave w of block q handles group
// pair {pw, 127-pw}, pw = 4q+w: exactly 33 key-tile iters per wave (perfect balance).
// K/V MFMA fragments straight from global (L2-hit); P per-wave LDS round-trip.
// NO __syncthreads in this kernel.
#define PST 72

__global__ __launch_bounds__(256)
void attn_k(const us* __restrict__ Qg,
            const us* __restrict__ Kg,
            const us* __restrict__ Vt,   // V^T [B,H,D,T]
            us* __restrict__ Og)
{
    __shared__ __align__(16) us Ps[4][16 * PST];   // per-wave P[m][key]

    const int tid  = threadIdx.x;
    const int wave = tid >> 6, lane = tid & 63;
    const int quad = lane >> 4, l16 = lane & 15;

    // XCD-locality decode: xcd = id%8 (round-robin dispatch heuristic)
    const int id  = blockIdx.x;
    const int xcd = id & 7, s = id >> 3;           // s in 0..95
    const int bh  = xcd + 8 * (s >> 4);            // head 0..47, fixed XCD
    const int q   = s & 15;                        // 0..15
    const int pw  = 4 * q + wave;                  // wave's pair index 0..63

    const size_t base  = (size_t)bh * TT * DH;     // Q/K
    const size_t baseV = (size_t)bh * DH * TT;     // V^T
    const int b = bh / NH, h = bh % NH;
    us* myP = Ps[wave];

    const f32x4 zero4 = {0.f, 0.f, 0.f, 0.f};

#pragma unroll 1
    for (int seg = 0; seg < 2; ++seg) {
        const int g   = seg ? 127 - pw : pw;       // 16-row group index 0..127
        const int nkt = (g >> 2) + 1;              // key tiles of 64
        const int m   = g * 16 + l16;              // this lane's query row

        bf16x8 qf0 = ld_frag(Qg + base + (size_t)m * DH + quad * 8);
        bf16x8 qf1 = ld_frag(Qg + base + (size_t)m * DH + 32 + quad * 8);

        f32x4 o[4];
#pragma unroll
        for (int i = 0; i < 4; ++i) o[i] = zero4;
        float mr = -INFINITY, lr = 0.f;

#pragma unroll 1
        for (int j = 0; j < nkt; ++j) {
            const us* kb = Kg + base  + (size_t)j * 64 * DH;
            const us* vb = Vt + baseV + j * 64;

            // K frags (A-operand) straight from L2: rows sub*16+l16, halves 0/1
            bf16x8 kf[4][2];
#pragma unroll
            for (int sub = 0; sub < 4; ++sub)
#pragma unroll
                for (int hh = 0; hh < 2; ++hh)
                    kf[sub][hh] = ld_frag(kb + (size_t)(sub * 16 + l16) * DH + hh * 32 + quad * 8);

            // S^T = K Q^T : rows = key, col = m (l16)
            f32x4 s4[4];
#pragma unroll
            for (int sub = 0; sub < 4; ++sub) {
                f32x4 t = __builtin_amdgcn_mfma_f32_16x16x32_bf16(kf[sub][0], qf0, zero4, 0, 0, 0);
                s4[sub]  = __builtin_amdgcn_mfma_f32_16x16x32_bf16(kf[sub][1], qf1, t, 0, 0, 0);
            }

            // V^T frags (A-operand) from L2: rows dsub*16+l16, key chunks kc*32+quad*8
            bf16x8 vf[4][2];
#pragma unroll
            for (int dsub = 0; dsub < 4; ++dsub)
#pragma unroll
                for (int kc = 0; kc < 2; ++kc)
                    vf[dsub][kc] = ld_frag(vb + (size_t)(dsub * 16 + l16) * TT + kc * 32 + quad * 8);

            // diagonal mask on last tile
            if (j == nkt - 1) {
#pragma unroll
                for (int sub = 0; sub < 4; ++sub)
#pragma unroll
                    for (int reg = 0; reg < 4; ++reg)
                        if (j * 64 + sub * 16 + quad * 4 + reg > m) s4[sub][reg] = -INFINITY;
            }

            // per-lane online softmax (16 vals + 2 shuffles)
            float mx = -INFINITY;
#pragma unroll
            for (int sub = 0; sub < 4; ++sub)
#pragma unroll
                for (int reg = 0; reg < 4; ++reg) mx = fmaxf(mx, s4[sub][reg]);
            mx = fmaxf(mx, __shfl_xor(mx, 16));
            mx = fmaxf(mx, __shfl_xor(mx, 32));
            float mnew = fmaxf(mr, mx);
            float alpha = exp2f(mr - mnew);
            float rs = 0.f;
#pragma unroll
            for (int sub = 0; sub < 4; ++sub) {
                float p0 = exp2f(s4[sub][0] - mnew), p1 = exp2f(s4[sub][1] - mnew);
                float p2 = exp2f(s4[sub][2] - mnew), p3 = exp2f(s4[sub][3] - mnew);
                rs += (p0 + p1) + (p2 + p3);
                uint2 pk; pk.x = pack2bf(p0, p1); pk.y = pack2bf(p2, p3);
                *reinterpret_cast<uint2*>(&myP[l16 * PST + sub * 16 + quad * 4]) = pk;
            }
            rs += __shfl_xor(rs, 16);
            rs += __shfl_xor(rs, 32);
            lr = lr * alpha + rs;
            mr = mnew;
#pragma unroll
            for (int d = 0; d < 4; ++d) o[d] *= alpha;

            // O^T += V^T P (same-wave LDS dep -> compiler inserts waits, no barrier)
#pragma unroll
            for (int kc = 0; kc < 2; ++kc) {
                bf16x8 pf = *reinterpret_cast<const bf16x8*>(&myP[l16 * PST + kc * 32 + quad * 8]);
#pragma unroll
                for (int d = 0; d < 4; ++d)
                    o[d] = __builtin_amdgcn_mfma_f32_16x16x32_bf16(vf[d][kc], pf, o[d], 0, 0, 0);
            }
        }

        // epilogue: O^T[d][m] -> att[b, t=m, h*64+d], 8B packed stores
        const float inv = 1.f / lr;
        us* orow = Og + ((size_t)(b * TT + m)) * CC + h * DH;
#pragma unroll
        for (int d = 0; d < 4; ++d) {
            uint2 pk;
            pk.x = pack2bf(o[d][0] * inv, o[d][1] * inv);
            pk.y = pack2bf(o[d][2] * inv, o[d][3] * inv);
            *reinterpret_cast<uint2*>(orow + d * 16 + quad * 4) = pk;
        }
    }
}

// ---------- launch ----------
extern "C" void kernel_launch(void* const* d_in, const int* in_sizes, int n_in,
                              void* d_out, int out_size, void* d_ws, size_t ws_size,
                              hipStream_t stream)
{
    const float* x      = (const float*)d_in[0];
    const float* w_attn = (const float*)d_in[1];
    const float* b_attn = (const float*)d_in[2];
    const float* w_proj = (const float*)d_in[3];
    const float* b_proj = (const float*)d_in[4];
    float* out = (float*)d_out;

    char* ws = (char*)d_ws;
    size_t off = 0;
    auto alloc = [&](size_t bytes) {
        void* p = ws + off;
        off += (bytes + 255) & ~(size_t)255;
        return p;
    };
    us* wtA = (us*)alloc((size_t)(3 * CC) * CC * 2);  // [2304][768] bf16
    us* wtP = (us*)alloc((size_t)CC * CC * 2);        // [768][768]  bf16
    us* xb  = (us*)alloc((size_t)MM * CC * 2);        // x as bf16
    us* Qb  = (us*)alloc((size_t)MM * CC * 2);        // [B,H,T,D]
    us* Kb  = (us*)alloc((size_t)MM * CC * 2);        // [B,H,T,D]
    us* Vtb = (us*)alloc((size_t)MM * CC * 2);        // V^T [B,H,D,T]
    us* att = (us*)alloc((size_t)MM * CC * 2);        // [B,T,C]

    cast_k<<<1024, 256, 0, stream>>>(x, xb, MM * CC / 4);
    transpose_k<<<dim3((3 * CC) / 32, CC / 32), dim3(32, 8), 0, stream>>>(w_attn, wtA, CC, 3 * CC);
    transpose_k<<<dim3(CC / 32, CC / 32), dim3(32, 8), 0, stream>>>(w_proj, wtP, CC, CC);

    gemm_bt<1><<<dim3((3 * CC) / BN, MM / BM), 256, 0, stream>>>(
        xb, wtA, b_attn, nullptr, Qb, Kb, Vtb, MM, 3 * CC, CC);

    attn_k<<<dim3(16 * BB * NH), 256, 0, stream>>>(Qb, Kb, Vtb, att);

    gemm_bt<0><<<dim3(CC / BN, MM / BM), 256, 0, stream>>>(
        att, wtP, b_proj, out, nullptr, nullptr, nullptr, MM, CC, CC);

    (void)in_sizes; (void)n_in; (void)out_size; (void)ws_size;
}

// Round 11
// 302.648 us; speedup vs baseline: 1.1411x; 1.1411x over previous
//
#include <hip/hip_runtime.h>
#include <cstdint>
#include <cstddef>

// ---------- types / helpers ----------
typedef __bf16 bf16x8 __attribute__((ext_vector_type(8)));
typedef float  f32x4  __attribute__((ext_vector_type(4)));
typedef unsigned short us;

#define DEV static __device__ __forceinline__

DEV us f2bf(float f) {
    unsigned int u = __builtin_bit_cast(unsigned int, f);
    u += 0x7FFFu + ((u >> 16) & 1u);   // RNE
    return (us)(u >> 16);
}
DEV unsigned int pack2bf(float a, float b) {   // [lo=a, hi=b], round-half-up (cheap)
    unsigned int ua = __builtin_bit_cast(unsigned int, a) + 0x8000u;
    unsigned int ub = __builtin_bit_cast(unsigned int, b) + 0x8000u;
    return (ua >> 16) | (ub & 0xFFFF0000u);    // -> v_perm_b32
}

DEV void gll16(const void* g, void* l) {   // 16B global->LDS direct (wave: +lane*16)
    __builtin_amdgcn_global_load_lds(
        (const __attribute__((address_space(1))) unsigned int*)g,
        (__attribute__((address_space(3))) unsigned int*)l, 16, 0, 0);
}

DEV bf16x8 ld_frag(const us* p) {
    return __builtin_bit_cast(bf16x8, *reinterpret_cast<const uint4*>(p));
}

// ---------- problem constants ----------
#define BB 4
#define TT 2048
#define CC 768
#define NH 12
#define DH 64
#define MM (BB*TT)          // 8192
#define QSCALE 0.1803368801111144f   // 0.125 * log2(e): softmax via exp2

// ---------- cast f32 -> bf16 ----------
__global__ __launch_bounds__(256)
void cast_k(const float* __restrict__ x, us* __restrict__ xb, int n4)
{
    int i = blockIdx.x * 256 + threadIdx.x;
    int stride = gridDim.x * 256;
    for (; i < n4; i += stride) {
        float4 f = reinterpret_cast<const float4*>(x)[i];
        ushort4 o;
        o.x = f2bf(f.x); o.y = f2bf(f.y); o.z = f2bf(f.z); o.w = f2bf(f.w);
        reinterpret_cast<ushort4*>(xb)[i] = o;
    }
}

// ---------- transpose f32 -> bf16: dst[Cc][R] = bf16(src[R][Cc]) ----------
__global__ __launch_bounds__(256)
void transpose_k(const float* __restrict__ src,
                 us* __restrict__ dst, int R, int Cc)
{
    __shared__ float tile[32][33];
    int c0 = blockIdx.x * 32, r0 = blockIdx.y * 32;
    int tx = threadIdx.x, ty = threadIdx.y;
#pragma unroll
    for (int i = 0; i < 4; ++i)
        tile[ty + i*8][tx] = src[(size_t)(r0 + ty + i*8) * Cc + c0 + tx];
    __syncthreads();
#pragma unroll
    for (int i = 0; i < 4; ++i)
        dst[(size_t)(c0 + ty + i*8) * R + r0 + tx] = f2bf(tile[tx][ty + i*8]);
}

// ---------- GEMM: C[M,N] = A[M,K](bf16) * Bt[N,K]^T + bias[N] ----------
// MODE 0: store f32 to Cout
// MODE 1: scatter qkv -> Qo(scaled)[B,H,T,D] / Ko[B,H,T,D] / Vo^T[B,H,D,T] bf16
#define BM 128
#define BN 128
#define BK 32

template<int MODE>
__global__ __launch_bounds__(256)
void gemm_bt(const us* __restrict__ A,
             const us* __restrict__ Bt,
             const float* __restrict__ bias,
             float* __restrict__ Cout,
             us* __restrict__ Qo, us* __restrict__ Ko, us* __restrict__ Vo,
             int M, int N, int K)
{
    __shared__ __align__(16) us As[BM * BK];
    __shared__ __align__(16) us Bs[BN * BK];

    const int tid  = threadIdx.x;
    const int wave = tid >> 6, lane = tid & 63;
    const int quad = lane >> 4, l16 = lane & 15;
    const int waveM = (wave >> 1) * 64, waveN = (wave & 1) * 64;
    const int m0 = blockIdx.y * BM, n0 = blockIdx.x * BN;

    const f32x4 zero4 = {0.f, 0.f, 0.f, 0.f};
    f32x4 acc[4][4];
#pragma unroll
    for (int i = 0; i < 4; ++i)
#pragma unroll
        for (int j = 0; j < 4; ++j) acc[i][j] = zero4;

    const int lrow = lane >> 2, lch = (lane & 3) * 8;
    const int nk = K / BK;
    for (int kt = 0; kt < nk; ++kt) {
#pragma unroll
        for (int c = 0; c < 2; ++c) {
            int rb = (wave * 2 + c) * 16;
            int row = rb + lrow;
            gll16(A  + (size_t)(m0 + row) * K + kt * BK + lch, &As[rb * BK]);
            gll16(Bt + (size_t)(n0 + row) * K + kt * BK + lch, &Bs[rb * BK]);
        }
        __syncthreads();

        bf16x8 af[4], bfv[4];
#pragma unroll
        for (int mi = 0; mi < 4; ++mi)
            af[mi] = *reinterpret_cast<const bf16x8*>(&As[(waveM + mi * 16 + l16) * BK + quad * 8]);
#pragma unroll
        for (int ni = 0; ni < 4; ++ni)
            bfv[ni] = *reinterpret_cast<const bf16x8*>(&Bs[(waveN + ni * 16 + l16) * BK + quad * 8]);
#pragma unroll
        for (int mi = 0; mi < 4; ++mi)
#pragma unroll
            for (int ni = 0; ni < 4; ++ni)
                acc[mi][ni] = __builtin_amdgcn_mfma_f32_16x16x32_bf16(af[mi], bfv[ni], acc[mi][ni], 0, 0, 0);
        __syncthreads();
    }

    // epilogue: C/D layout col = l16, row = quad*4 + reg
#pragma unroll
    for (int mi = 0; mi < 4; ++mi) {
#pragma unroll
        for (int ni = 0; ni < 4; ++ni) {
            int n = n0 + waveN + ni * 16 + l16;
            float bv = bias[n];
            int mg = m0 + waveM + mi * 16 + quad * 4;   // first of 4 consecutive m
            if (MODE == 0) {
#pragma unroll
                for (int reg = 0; reg < 4; ++reg)
                    Cout[(size_t)(mg + reg) * N + n] = acc[mi][ni][reg] + bv;
            } else {
                int which = n / CC, c2 = n % CC;
                int h = c2 >> 6, d = c2 & 63;
                int b = mg >> 11, t0 = mg & 2047;
                if (which == 2) {
                    // V^T [B,H,D,T]: 4 consecutive t -> one 8B store
                    ushort4 pk;
                    pk.x = f2bf(acc[mi][ni][0] + bv);
                    pk.y = f2bf(acc[mi][ni][1] + bv);
                    pk.z = f2bf(acc[mi][ni][2] + bv);
                    pk.w = f2bf(acc[mi][ni][3] + bv);
                    *reinterpret_cast<ushort4*>(Vo + ((size_t)(b * NH + h) * DH + d) * TT + t0) = pk;
                } else {
#pragma unroll
                    for (int reg = 0; reg < 4; ++reg) {
                        size_t off = ((size_t)(b * NH + h) * TT + t0 + reg) * DH + d;
                        float v = acc[mi][ni][reg] + bv;
                        if (which == 0) Qo[off] = f2bf(v * QSCALE);
                        else            Ko[off] = f2bf(v);
                    }
                }
            }
        }
    }
}

// ---------- flash attention (causal): one wave = 64 q-rows, barrier-free, L2-direct ----------
// 1536 blocks x 64 threads. Dispatch model: XCD = id&7, CU = (id>>3)&31, slot = id>>8.
// Complementary groups {g, 31-g} land in consecutive slots of the same CU -> every CU
// does exactly 99 key-tile iters. Heads pinned per-XCD (6 heads x 512KB = 3MB <= 4MB L2).
// 4 MFMA subgroups (16 rows each) share every K/V fragment -> half the L2 traffic of r9.
// NO __syncthreads. P per-wave LDS round-trip only.
#define PST 72

__global__ __launch_bounds__(64)
void attn_k(const us* __restrict__ Qg,
            const us* __restrict__ Kg,
            const us* __restrict__ Vt,   // V^T [B,H,D,T]
            us* __restrict__ Og)
{
    __shared__ __align__(16) us Ps[64 * PST];   // P[m 0..63][key 0..63]

    const int lane = threadIdx.x;
    const int quad = lane >> 4, l16 = lane & 15;

    // balanced XCD-local decode
    const int id   = blockIdx.x;
    const int xcd  = id & 7;
    const int cu   = (id >> 3) & 31;
    const int slot = id >> 8;                  // 0..5
    const int hp   = slot >> 1, par = slot & 1;
    const int bh   = xcd + 8 * (2 * hp + (cu >> 4));   // head 0..47, fixed XCD
    const int ga   = cu & 15;
    const int g    = par ? 31 - ga : ga;       // 64-row q-group 0..31
    const int nkt  = g + 1;                    // causal key tiles

    const size_t base  = (size_t)bh * TT * DH; // Q/K
    const size_t baseV = (size_t)bh * DH * TT; // V^T
    const int b = bh / NH, h = bh % NH;

    const f32x4 zero4 = {0.f, 0.f, 0.f, 0.f};

    // Q fragments for 4 subgroups (B-operand [m][k]); rows m = g*64 + grp*16 + l16
    bf16x8 qf[4][2];
#pragma unroll
    for (int grp = 0; grp < 4; ++grp) {
        const us* qrow = Qg + base + (size_t)(g * 64 + grp * 16 + l16) * DH;
        qf[grp][0] = ld_frag(qrow + quad * 8);
        qf[grp][1] = ld_frag(qrow + 32 + quad * 8);
    }

    f32x4 o[4][4];
#pragma unroll
    for (int grp = 0; grp < 4; ++grp)
#pragma unroll
        for (int d = 0; d < 4; ++d) o[grp][d] = zero4;
    float mr[4] = {-INFINITY, -INFINITY, -INFINITY, -INFINITY};
    float lr[4] = {0.f, 0.f, 0.f, 0.f};

#pragma unroll 1
    for (int j = 0; j < nkt; ++j) {
        const us* kb = Kg + base  + (size_t)j * 64 * DH;
        const us* vb = Vt + baseV + j * 64;

        // K frags (A-operand) straight from L2 — shared by all 4 subgroups
        bf16x8 kf[4][2];
#pragma unroll
        for (int sub = 0; sub < 4; ++sub) {
            kf[sub][0] = ld_frag(kb + (size_t)(sub * 16 + l16) * DH + quad * 8);
            kf[sub][1] = ld_frag(kb + (size_t)(sub * 16 + l16) * DH + 32 + quad * 8);
        }
        // V^T frags (A-operand) — also shared; issue early, consumed at PV
        bf16x8 vf[4][2];
#pragma unroll
        for (int dsub = 0; dsub < 4; ++dsub) {
            vf[dsub][0] = ld_frag(vb + (size_t)(dsub * 16 + l16) * TT + quad * 8);
            vf[dsub][1] = ld_frag(vb + (size_t)(dsub * 16 + l16) * TT + 32 + quad * 8);
        }

        const bool diag = (j == nkt - 1);

        // per subgroup: S^T = K Q^T, mask, online softmax, P -> LDS
#pragma unroll
        for (int grp = 0; grp < 4; ++grp) {
            const int m = g * 64 + grp * 16 + l16;
            f32x4 s4[4];
#pragma unroll
            for (int sub = 0; sub < 4; ++sub) {
                f32x4 t = __builtin_amdgcn_mfma_f32_16x16x32_bf16(kf[sub][0], qf[grp][0], zero4, 0, 0, 0);
                s4[sub]  = __builtin_amdgcn_mfma_f32_16x16x32_bf16(kf[sub][1], qf[grp][1], t, 0, 0, 0);
            }
            if (diag) {
#pragma unroll
                for (int sub = 0; sub < 4; ++sub)
#pragma unroll
                    for (int reg = 0; reg < 4; ++reg)
                        if (j * 64 + sub * 16 + quad * 4 + reg > m) s4[sub][reg] = -INFINITY;
            }
            float mx = -INFINITY;
#pragma unroll
            for (int sub = 0; sub < 4; ++sub)
#pragma unroll
                for (int reg = 0; reg < 4; ++reg) mx = fmaxf(mx, s4[sub][reg]);
            mx = fmaxf(mx, __shfl_xor(mx, 16));
            mx = fmaxf(mx, __shfl_xor(mx, 32));
            float mnew = fmaxf(mr[grp], mx);
            float alpha = exp2f(mr[grp] - mnew);
            float rs = 0.f;
#pragma unroll
            for (int sub = 0; sub < 4; ++sub) {
                float p0 = exp2f(s4[sub][0] - mnew), p1 = exp2f(s4[sub][1] - mnew);
                float p2 = exp2f(s4[sub][2] - mnew), p3 = exp2f(s4[sub][3] - mnew);
                rs += (p0 + p1) + (p2 + p3);
                uint2 pk; pk.x = pack2bf(p0, p1); pk.y = pack2bf(p2, p3);
                *reinterpret_cast<uint2*>(&Ps[(grp * 16 + l16) * PST + sub * 16 + quad * 4]) = pk;
            }
            rs += __shfl_xor(rs, 16);
            rs += __shfl_xor(rs, 32);
            lr[grp] = lr[grp] * alpha + rs;
            mr[grp] = mnew;
#pragma unroll
            for (int d = 0; d < 4; ++d) o[grp][d] *= alpha;
        }

        // per subgroup: O^T += V^T P (V frags shared; same-wave LDS dep, no barrier)
#pragma unroll
        for (int grp = 0; grp < 4; ++grp) {
#pragma unroll
            for (int kc = 0; kc < 2; ++kc) {
                bf16x8 pf = *reinterpret_cast<const bf16x8*>(&Ps[(grp * 16 + l16) * PST + kc * 32 + quad * 8]);
#pragma unroll
                for (int d = 0; d < 4; ++d)
                    o[grp][d] = __builtin_amdgcn_mfma_f32_16x16x32_bf16(vf[d][kc], pf, o[grp][d], 0, 0, 0);
            }
        }
    }

    // epilogue: O^T[d][m] -> att[b, t=m, h*64+d], 8B packed stores
#pragma unroll
    for (int grp = 0; grp < 4; ++grp) {
        const int m = g * 64 + grp * 16 + l16;
        const float inv = 1.f / lr[grp];
        us* orow = Og + ((size_t)(b * TT + m)) * CC + h * DH;
#pragma unroll
        for (int d = 0; d < 4; ++d) {
            uint2 pk;
            pk.x = pack2bf(o[grp][d][0] * inv, o[grp][d][1] * inv);
            pk.y = pack2bf(o[grp][d][2] * inv, o[grp][d][3] * inv);
            *reinterpret_cast<uint2*>(orow + d * 16 + quad * 4) = pk;
        }
    }
}

// ---------- launch ----------
extern "C" void kernel_launch(void* const* d_in, const int* in_sizes, int n_in,
                              void* d_out, int out_size, void* d_ws, size_t ws_size,
                              hipStream_t stream)
{
    const float* x      = (const float*)d_in[0];
    const float* w_attn = (const float*)d_in[1];
    const float* b_attn = (const float*)d_in[2];
    const float* w_proj = (const float*)d_in[3];
    const float* b_proj = (const float*)d_in[4];
    float* out = (float*)d_out;

    char* ws = (char*)d_ws;
    size_t off = 0;
    auto alloc = [&](size_t bytes) {
        void* p = ws + off;
        off += (bytes + 255) & ~(size_t)255;
        return p;
    };
    us* wtA = (us*)alloc((size_t)(3 * CC) * CC * 2);  // [2304][768] bf16
    us* wtP = (us*)alloc((size_t)CC * CC * 2);        // [768][768]  bf16
    us* xb  = (us*)alloc((size_t)MM * CC * 2);        // x as bf16
    us* Qb  = (us*)alloc((size_t)MM * CC * 2);        // [B,H,T,D]
    us* Kb  = (us*)alloc((size_t)MM * CC * 2);        // [B,H,T,D]
    us* Vtb = (us*)alloc((size_t)MM * CC * 2);        // V^T [B,H,D,T]
    us* att = (us*)alloc((size_t)MM * CC * 2);        // [B,T,C]

    cast_k<<<1024, 256, 0, stream>>>(x, xb, MM * CC / 4);
    transpose_k<<<dim3((3 * CC) / 32, CC / 32), dim3(32, 8), 0, stream>>>(w_attn, wtA, CC, 3 * CC);
    transpose_k<<<dim3(CC / 32, CC / 32), dim3(32, 8), 0, stream>>>(w_proj, wtP, CC, CC);

    gemm_bt<1><<<dim3((3 * CC) / BN, MM / BM), 256, 0, stream>>>(
        xb, wtA, b_attn, nullptr, Qb, Kb, Vtb, MM, 3 * CC, CC);

    attn_k<<<dim3(1536), 64, 0, stream>>>(Qb, Kb, Vtb, att);

    gemm_bt<0><<<dim3(CC / BN, MM / BM), 256, 0, stream>>>(
        att, wtP, b_proj, out, nullptr, nullptr, nullptr, MM, CC, CC);

    (void)in_sizes; (void)n_in; (void)out_size; (void)ws_size;
}